// Round 17
// baseline (2197.976 us; speedup 1.0000x reference)
//
#include <hip/hip_runtime.h>
#include <math.h>

// ---------------------------------------------------------------------------
// CapsuleNet forward. R17: exact R14 structure (747us proven; R16's dec12 +
// squash_v-folding trims regressed 24us -> reverted) with ONE change:
// __launch_bounds__(256,5) on pc_mfma_k. R16 evidence: VGPR=104 caps
// residency at 4 blocks/CU (grid 1296 vs capacity 1024 -> 272-block tail,
// 4-way interleave). <=102 VGPR gives 5 blocks/CU, capacity 1280.
// ---------------------------------------------------------------------------

typedef unsigned short u16;
typedef short bf16x8 __attribute__((ext_vector_type(8)));
typedef float f32x4 __attribute__((ext_vector_type(4)));

#define PS 2359296   // 9216*256, one y2 partial buffer
#define KSPLIT 9
#define KSLICE 2304  // 20736/9
#define NSTAGE 36    // 2304/64

__device__ u16 g_x1b[256 * 400 * 256];          // conv1 out NHWC bf16 (52 MB)
__device__ u16 g_wbF[648 * 16 * 512];           // pc_w bf16, MFMA frag order (10.6 MB)
__device__ u16 g_y2p[(size_t)KSPLIT * PS];      // pc GEMM K-partials bf16 (42.5 MB)
__device__ float g_u[256 * 1152 * 8];           // squashed primary caps
__device__ u16 g_WU[(size_t)256 * 1152 * 160];  // u_hat bf16 (94.4 MB)
__device__ float g_ssum[3 * 256 * 160];
__device__ float g_v[3 * 256 * 160];
__device__ float g_h1[256 * 512];
__device__ float g_h2[256 * 1024];

__device__ __forceinline__ u16 f2bf(float f) {
  union { float f; unsigned u; } v; v.f = f;
  unsigned r = (v.u + 0x7FFFu + ((v.u >> 16) & 1u)) >> 16;  // RNE
  return (u16)r;
}
__device__ __forceinline__ float bf2f(u16 h) {
  union { unsigned u; float f; } v; v.u = ((unsigned)h) << 16;
  return v.f;
}

// ---------------- zero the atomic accumulators ----------------
__global__ __launch_bounds__(256) void zero_ssum_k() {
  int i = blockIdx.x * 256 + threadIdx.x;
  if (i < 3 * 256 * 160) g_ssum[i] = 0.f;
}

// ------ pc_w fp32 [oc][ic][kp] -> bf16 fragment order --------------------
__global__ __launch_bounds__(256) void wconv_k(const float* __restrict__ w) {
  __shared__ float Ws[256 * 16];   // [ic][ocl] 16 KB
  int n16 = blockIdx.x;   // 0..15
  int kp = blockIdx.y;    // 0..80
  int t = threadIdx.x;
  for (int idx = t; idx < 4096; idx += 256) {
    int ic = idx >> 4;
    int ocl = idx & 15;
    Ws[idx] = w[(size_t)(n16 * 16 + ocl) * 20736 + ic * 81 + kp];
  }
  __syncthreads();
  for (int idx = t; idx < 4096; idx += 256) {
    int c = idx >> 9;          // k-chunk within this kp: 0..7
    int r = idx & 511;
    int ll = r >> 3, j = r & 7;
    int ic = c * 32 + ((ll >> 4) << 3) + j;
    g_wbF[(((size_t)kp * 8 + c) * 16 + n16) * 512 + r] = f2bf(Ws[ic * 16 + (ll & 15)]);
  }
}

// ---------------- conv1 + relu -> bf16 NHWC (register-blocked) ----------------
__global__ __launch_bounds__(256) void conv1_relu_k(
    const float* __restrict__ in, const float* __restrict__ w,
    const float* __restrict__ bias) {
  __shared__ float in_s[784];
  __shared__ float w_s[64 * 81];
  int b = blockIdx.x;
  int oc0 = blockIdx.y * 64;
  int t = threadIdx.x;
  for (int i = t; i < 784; i += 256) in_s[i] = in[b * 784 + i];
  for (int i = t; i < 64 * 81; i += 256) w_s[i] = w[oc0 * 81 + i];
  __syncthreads();

  int ocl = t & 63;
  int r = t >> 6;            // wave-uniform
  float w_r[81];
#pragma unroll
  for (int i = 0; i < 81; i++) w_r[i] = w_s[ocl * 81 + i];
  float bv = bias[oc0 + ocl];
  u16* outb = g_x1b + (size_t)b * 102400 + oc0 + ocl;

#pragma unroll
  for (int rr = 0; rr < 5; rr++) {
    int oy = r + rr * 4;     // wave-uniform
    float acc[20];
#pragma unroll
    for (int ox = 0; ox < 20; ox++) acc[ox] = bv;
#pragma unroll
    for (int ky = 0; ky < 9; ky++) {
      float in_r[28];
      const float* irow = &in_s[(oy + ky) * 28];
#pragma unroll
      for (int c = 0; c < 28; c++) in_r[c] = irow[c];   // broadcast reads
#pragma unroll
      for (int kx = 0; kx < 9; kx++) {
        float wv = w_r[ky * 9 + kx];
#pragma unroll
        for (int ox = 0; ox < 20; ox++)
          acc[ox] = fmaf(in_r[ox + kx], wv, acc[ox]);
      }
    }
#pragma unroll
    for (int ox = 0; ox < 20; ox++)
      outb[(oy * 20 + ox) * 256] = f2bf(fmaxf(acc[ox], 0.f));
  }
}

// ---------------- pc conv: bf16 MFMA GEMM, full-N blocks -------------------
// __launch_bounds__(256,5): cap VGPR at 102 -> 5 blocks/CU residency.
__global__ __launch_bounds__(256, 5) void pc_mfma_k() {
  __shared__ u16 As[64 * 72];  // 64 rows x 64 k, padded row stride 72
  int t = threadIdx.x;
  int m0 = blockIdx.x * 64;
  int ks0 = blockIdx.y * KSLICE;
  u16* outp = g_y2p + (size_t)blockIdx.y * PS;

  int w = t >> 6, l = t & 63, quad = l >> 4, c15 = l & 15;
  int wm = w & 1, wn = w >> 1;

  int sr = t >> 3;
  int sc = t & 7;
  int fixed0, fixed1;
  {
    int m = m0 + sr;
    int bb = m / 36;
    int s = m - bb * 36;
    int oy = s / 6;
    int ox = s - oy * 6;
    fixed0 = bb * 102400 + oy * 10240 + ox * 512 + sc * 8;
    m += 32;
    bb = m / 36;
    s = m - bb * 36;
    oy = s / 6;
    ox = s - oy * 6;
    fixed1 = bb * 102400 + oy * 10240 + ox * 512 + sc * 8;
  }

  size_t bofs[8];
#pragma unroll
  for (int g = 0; g < 2; g++)
#pragma unroll
    for (int jn = 0; jn < 4; jn++)
      bofs[g * 4 + jn] = ((size_t)(g * 8 + wn * 4 + jn)) * 512 + l * 8;

  f32x4 acc[2][8];
#pragma unroll
  for (int i = 0; i < 2; i++)
#pragma unroll
    for (int j = 0; j < 8; j++) acc[i][j] = (f32x4){0.f, 0.f, 0.f, 0.f};

  uint4 ap0, ap1;
  bf16x8 bpf[2][8];
  {
    int k0 = ks0;
    int kp = k0 >> 8, ic0 = k0 & 255;
    int ky = kp / 9, kx = kp - ky * 9;
    int off = ky * 5120 + kx * 256 + ic0;
    ap0 = *(const uint4*)(g_x1b + fixed0 + off);
    ap1 = *(const uint4*)(g_x1b + fixed1 + off);
    const u16* bp = g_wbF + ((size_t)(k0 >> 5) << 13);
#pragma unroll
    for (int kk = 0; kk < 2; kk++)
#pragma unroll
      for (int jn = 0; jn < 8; jn++)
        bpf[kk][jn] = *(const bf16x8*)(bp + (kk << 13) + bofs[jn]);
  }

  for (int st = 0; st < NSTAGE; st++) {
    __syncthreads();
    *(uint4*)&As[sr * 72 + sc * 8] = ap0;
    *(uint4*)&As[(sr + 32) * 72 + sc * 8] = ap1;
    __syncthreads();
    if (st < NSTAGE - 1) {
      int k0 = ks0 + (st + 1) * 64;
      int kp = k0 >> 8, ic0 = k0 & 255;
      int ky = kp / 9, kx = kp - ky * 9;
      int off = ky * 5120 + kx * 256 + ic0;
      ap0 = *(const uint4*)(g_x1b + fixed0 + off);
      ap1 = *(const uint4*)(g_x1b + fixed1 + off);
    }
#pragma unroll
    for (int kk = 0; kk < 2; kk++) {
#pragma unroll
      for (int i = 0; i < 2; i++) {
        bf16x8 af = *(const bf16x8*)&As[(wm * 32 + i * 16 + c15) * 72 + kk * 32 + quad * 8];
#pragma unroll
        for (int jn = 0; jn < 8; jn++)
          acc[i][jn] = __builtin_amdgcn_mfma_f32_16x16x32_bf16(af, bpf[kk][jn], acc[i][jn], 0, 0, 0);
      }
    }
    if (st < NSTAGE - 1) {
      int k0n = ks0 + (st + 1) * 64;
      const u16* bp = g_wbF + ((size_t)(k0n >> 5) << 13);
#pragma unroll
      for (int kk = 0; kk < 2; kk++)
#pragma unroll
        for (int jn = 0; jn < 8; jn++)
          bpf[kk][jn] = *(const bf16x8*)(bp + (kk << 13) + bofs[jn]);
    }
  }
#pragma unroll
  for (int i = 0; i < 2; i++)
#pragma unroll
    for (int g = 0; g < 2; g++)
#pragma unroll
      for (int jn = 0; jn < 4; jn++) {
        int col = g * 128 + wn * 64 + jn * 16 + c15;
#pragma unroll
        for (int rg = 0; rg < 4; rg++) {
          int row = m0 + wm * 32 + i * 16 + quad * 4 + rg;
          outp[(size_t)row * 256 + col] = f2bf(acc[i][g * 4 + jn][rg]);
        }
      }
}

// ---------------- squash primary capsules (coalesced row-wise) -------------
__global__ __launch_bounds__(256) void squash_u_k(const float* __restrict__ pcb) {
  __shared__ float xs[256];
  __shared__ float scs[32];
  int m = blockIdx.x;          // 0..9215
  int t = threadIdx.x;
  int b = m / 36;
  int s = m - b * 36;
  float x = pcb[t];
  const u16* base = g_y2p + (size_t)m * 256 + t;
#pragma unroll
  for (int q = 0; q < KSPLIT; q++) x += bf2f(base[(size_t)q * PS]);
  xs[t] = x;
  __syncthreads();
  if (t < 32) {
    float sq = 0.f;
#pragma unroll
    for (int p = 0; p < 8; p++) {
      float v = xs[t + p * 32];
      sq = fmaf(v, v, sq);
    }
    scs[t] = (sq / (1.f + sq)) * rsqrtf(sq + 1e-7f);
  }
  __syncthreads();
  int g = t & 31, p = t >> 5;
  g_u[((size_t)b * 1152 + g * 36 + s) * 8 + p] = x * scs[g];
}

// ---------------- WU einsum (bf16 output) ----------------
__global__ __launch_bounds__(256) void wu_k(const float* __restrict__ W) {
  __shared__ float W_s[8][161];
  __shared__ float u_s[32][8];
  int n = blockIdx.x;
  int b0 = blockIdx.y * 32;
  int t = threadIdx.x;
  const float* Wn = W + (size_t)n * 1280;
  for (int i = t; i < 1280; i += 256) {
    int cd = i >> 3, p = i & 7;
    W_s[p][cd] = Wn[i];
  }
  {
    int bl = t >> 3, p = t & 7;
    u_s[bl][p] = g_u[(size_t)(b0 + bl) * 9216 + n * 8 + p];
  }
  __syncthreads();
#pragma unroll
  for (int i = 0; i < 20; i++) {
    int idx = t + 256 * i;
    int bl = idx / 160;
    int cd = idx - bl * 160;
    float acc = 0.f;
#pragma unroll
    for (int p = 0; p < 8; p++) acc = fmaf(u_s[bl][p], W_s[p][cd], acc);
    g_WU[((size_t)(b0 + bl) * 1152 + n) * 160 + cd] = f2bf(acc);
  }
}

// ---------------- iter0 reduction (bf16 input) ----------------
__global__ __launch_bounds__(256) void red0_k() {
  int b = blockIdx.x;
  int chunk = blockIdx.y;
  int t = threadIdx.x;
  if (t >= 160) return;
  const u16* base = g_WU + ((size_t)b * 1152 + chunk * 144) * 160 + t;
  float acc = 0.f;
  for (int n = 0; n < 144; n++) acc += bf2f(base[(size_t)n * 160]);
  atomicAdd(&g_ssum[b * 160 + t], 0.1f * acc);
}

// ---------------- squash of class capsules ----------------
__global__ void squash_v_k(int slot, float* __restrict__ clf, int write_clf) {
  int b = blockIdx.x;
  int c = threadIdx.x;
  if (c >= 10) return;
  const float* s = g_ssum + slot * 40960 + b * 160 + c * 16;
  float sq = 0.f;
#pragma unroll
  for (int d = 0; d < 16; d++) sq = fmaf(s[d], s[d], sq);
  float scale = (sq / (1.f + sq)) * rsqrtf(sq + 1e-7f);
  float* vo = g_v + slot * 40960 + b * 160 + c * 16;
#pragma unroll
  for (int d = 0; d < 16; d++) vo[d] = s[d] * scale;
  if (write_clf) clf[b * 10 + c] = scale * sqrtf(sq);
}

// ---------------- routing iteration (bf16 WU input) ----------------
template <int IT>
__global__ __launch_bounds__(256) void routing_iter_k() {
  int b = blockIdx.x;
  int nb = blockIdx.y;
  int t = threadIdx.x;
  int lane = t & 15;
  int grp = t >> 4;

  const float* v0 = g_v;
  const float* v1 = g_v + 40960;
  float* ssum_out = g_ssum + IT * 40960;

  float v0r[10], v1r[10];
#pragma unroll
  for (int c = 0; c < 10; c++) v0r[c] = v0[b * 160 + c * 16 + lane];
  if (IT == 2) {
#pragma unroll
    for (int c = 0; c < 10; c++) v1r[c] = v1[b * 160 + c * 16 + lane];
  }

  float acc[10];
#pragma unroll
  for (int c = 0; c < 10; c++) acc[c] = 0.f;

  for (int ni = 0; ni < 9; ni++) {
    int n = nb * 144 + grp * 9 + ni;
    const u16* row = g_WU + ((size_t)b * 1152 + n) * 160;
    float wu[10];
#pragma unroll
    for (int c = 0; c < 10; c++) wu[c] = bf2f(row[c * 16 + lane]);

    float bij[10];
#pragma unroll
    for (int c = 0; c < 10; c++) {
      float x = v0r[c] * wu[c];
      x += __shfl_xor(x, 1);
      x += __shfl_xor(x, 2);
      x += __shfl_xor(x, 4);
      x += __shfl_xor(x, 8);
      bij[c] = 0.1f * x;
    }

    if (IT == 2) {
      float mx = bij[0];
#pragma unroll
      for (int c = 1; c < 10; c++) mx = fmaxf(mx, bij[c]);
      float e[10], ssum = 0.f;
#pragma unroll
      for (int c = 0; c < 10; c++) {
        e[c] = __expf(bij[c] - mx);
        ssum += e[c];
      }
      float inv = 1.f / ssum;
#pragma unroll
      for (int c = 0; c < 10; c++) {
        float x = v1r[c] * wu[c];
        x += __shfl_xor(x, 1);
        x += __shfl_xor(x, 2);
        x += __shfl_xor(x, 4);
        x += __shfl_xor(x, 8);
        bij[c] = bij[c] + (e[c] * inv) * x;
      }
    }

    float mx = bij[0];
#pragma unroll
    for (int c = 1; c < 10; c++) mx = fmaxf(mx, bij[c]);
    float e[10], ssum = 0.f;
#pragma unroll
    for (int c = 0; c < 10; c++) {
      e[c] = __expf(bij[c] - mx);
      ssum += e[c];
    }
    float inv = 1.f / ssum;
#pragma unroll
    for (int c = 0; c < 10; c++) acc[c] = fmaf(e[c] * inv, wu[c], acc[c]);
  }
#pragma unroll
  for (int c = 0; c < 10; c++)
    atomicAdd(&ssum_out[b * 160 + c * 16 + lane], acc[c]);
}

// ---------------- decoder ----------------
__global__ __launch_bounds__(256) void dec1_k(const int* __restrict__ labels,
                                              const float* __restrict__ w1,
                                              const float* __restrict__ b1) {
  int b = blockIdx.y;
  int j = blockIdx.x * 256 + threadIdx.x;
  int lab = labels[b];
  const float* vv = g_v + 2 * 40960 + b * 160 + lab * 16;
  float acc = b1[j];
#pragma unroll
  for (int d = 0; d < 16; d++)
    acc = fmaf(vv[d], w1[(size_t)(lab * 16 + d) * 512 + j], acc);
  g_h1[b * 512 + j] = fmaxf(acc, 0.f);
}

// dec2: 2 batches per block — w2 stream reused 2x. Grid (4, 128).
__global__ __launch_bounds__(256) void dec2_k(const float* __restrict__ w2,
                                              const float* __restrict__ b2) {
  __shared__ float h_s[2][512];
  int b0 = blockIdx.y * 2;
  int j = blockIdx.x * 256 + threadIdx.x;
  int t = threadIdx.x;
  for (int i = t; i < 1024; i += 256) h_s[i >> 9][i & 511] = g_h1[b0 * 512 + i];
  __syncthreads();
  float a0 = b2[j], a1 = a0;
#pragma unroll 8
  for (int k = 0; k < 512; k++) {
    float wv = w2[(size_t)k * 1024 + j];
    a0 = fmaf(h_s[0][k], wv, a0);
    a1 = fmaf(h_s[1][k], wv, a1);
  }
  g_h2[b0 * 1024 + j] = fmaxf(a0, 0.f);
  g_h2[(b0 + 1) * 1024 + j] = fmaxf(a1, 0.f);
}

// dec3: 2 batches per block — w3 stream reused 2x. Grid (4, 128).
__global__ __launch_bounds__(256) void dec3_k(const float* __restrict__ w3,
                                              const float* __restrict__ b3,
                                              float* __restrict__ out) {
  __shared__ float h_s[2][1024];
  int b0 = blockIdx.y * 2;
  int t = threadIdx.x;
  for (int i = t; i < 2048; i += 256) h_s[i >> 10][i & 1023] = g_h2[b0 * 1024 + i];
  __syncthreads();
  if (t >= 196) return;
  int j = blockIdx.x * 196 + t;
  float a0 = b3[j], a1 = a0;
#pragma unroll 8
  for (int k = 0; k < 1024; k++) {
    float wv = w3[(size_t)k * 784 + j];
    a0 = fmaf(h_s[0][k], wv, a0);
    a1 = fmaf(h_s[1][k], wv, a1);
  }
  out[2560 + b0 * 784 + j] = 1.f / (1.f + __expf(-a0));
  out[2560 + (b0 + 1) * 784 + j] = 1.f / (1.f + __expf(-a1));
}

// ---------------------------------------------------------------------------
extern "C" void kernel_launch(void* const* d_in, const int* in_sizes, int n_in,
                              void* d_out, int out_size, void* d_ws,
                              size_t ws_size, hipStream_t stream) {
  const float* inputs = (const float*)d_in[0];
  const int* labels = (const int*)d_in[1];
  const float* conv1_w = (const float*)d_in[2];
  const float* conv1_b = (const float*)d_in[3];
  const float* pc_w = (const float*)d_in[4];
  const float* pc_b = (const float*)d_in[5];
  const float* rw = (const float*)d_in[6];
  const float* dw1 = (const float*)d_in[7];
  const float* db1 = (const float*)d_in[8];
  const float* dw2 = (const float*)d_in[9];
  const float* db2 = (const float*)d_in[10];
  const float* dw3 = (const float*)d_in[11];
  const float* db3 = (const float*)d_in[12];
  float* out = (float*)d_out;
  (void)d_ws; (void)ws_size; (void)in_sizes; (void)n_in;

  zero_ssum_k<<<(3 * 256 * 160 + 255) / 256, 256, 0, stream>>>();
  wconv_k<<<dim3(16, 81), 256, 0, stream>>>(pc_w);
  conv1_relu_k<<<dim3(256, 4), 256, 0, stream>>>(inputs, conv1_w, conv1_b);
  pc_mfma_k<<<dim3(144, KSPLIT), 256, 0, stream>>>();
  squash_u_k<<<9216, 256, 0, stream>>>(pc_b);
  wu_k<<<dim3(1152, 8), 256, 0, stream>>>(rw);
  red0_k<<<dim3(256, 8), 256, 0, stream>>>();
  squash_v_k<<<256, 64, 0, stream>>>(0, nullptr, 0);
  routing_iter_k<1><<<dim3(256, 8), 256, 0, stream>>>();
  squash_v_k<<<256, 64, 0, stream>>>(1, nullptr, 0);
  routing_iter_k<2><<<dim3(256, 8), 256, 0, stream>>>();
  squash_v_k<<<256, 64, 0, stream>>>(2, out, 1);
  dec1_k<<<dim3(2, 256), 256, 0, stream>>>(labels, dw1, db1);
  dec2_k<<<dim3(4, 128), 256, 0, stream>>>(dw2, db2);
  dec3_k<<<dim3(4, 128), 256, 0, stream>>>(dw3, db3, out);
}

// Round 18
// 742.351 us; speedup vs baseline: 2.9608x; 2.9608x over previous
//
#include <hip/hip_runtime.h>
#include <math.h>

// ---------------------------------------------------------------------------
// CapsuleNet forward. R18: exact R14 (747us proven). R17's launch_bounds(256,5)
// forced catastrophic spills (VGPR 48, 7GB scratch traffic) -> reverted.
// Single change vs R14: pc_mfma B-fragment offsets stored as 32-bit ints
// (g_wbF spans 10.6MB) to shave ~8 VGPR naturally: 104 -> <=102 crosses the
// 5-blocks/CU residency step (512/5=102.4) without allocator coercion.
// ---------------------------------------------------------------------------

typedef unsigned short u16;
typedef short bf16x8 __attribute__((ext_vector_type(8)));
typedef float f32x4 __attribute__((ext_vector_type(4)));

#define PS 2359296   // 9216*256, one y2 partial buffer
#define KSPLIT 9
#define KSLICE 2304  // 20736/9
#define NSTAGE 36    // 2304/64

__device__ u16 g_x1b[256 * 400 * 256];          // conv1 out NHWC bf16 (52 MB)
__device__ u16 g_wbF[648 * 16 * 512];           // pc_w bf16, MFMA frag order (10.6 MB)
__device__ u16 g_y2p[(size_t)KSPLIT * PS];      // pc GEMM K-partials bf16 (42.5 MB)
__device__ float g_u[256 * 1152 * 8];           // squashed primary caps
__device__ u16 g_WU[(size_t)256 * 1152 * 160];  // u_hat bf16 (94.4 MB)
__device__ float g_ssum[3 * 256 * 160];
__device__ float g_v[3 * 256 * 160];
__device__ float g_h1[256 * 512];
__device__ float g_h2[256 * 1024];

__device__ __forceinline__ u16 f2bf(float f) {
  union { float f; unsigned u; } v; v.f = f;
  unsigned r = (v.u + 0x7FFFu + ((v.u >> 16) & 1u)) >> 16;  // RNE
  return (u16)r;
}
__device__ __forceinline__ float bf2f(u16 h) {
  union { unsigned u; float f; } v; v.u = ((unsigned)h) << 16;
  return v.f;
}

// ---------------- zero the atomic accumulators ----------------
__global__ __launch_bounds__(256) void zero_ssum_k() {
  int i = blockIdx.x * 256 + threadIdx.x;
  if (i < 3 * 256 * 160) g_ssum[i] = 0.f;
}

// ------ pc_w fp32 [oc][ic][kp] -> bf16 fragment order --------------------
__global__ __launch_bounds__(256) void wconv_k(const float* __restrict__ w) {
  __shared__ float Ws[256 * 16];   // [ic][ocl] 16 KB
  int n16 = blockIdx.x;   // 0..15
  int kp = blockIdx.y;    // 0..80
  int t = threadIdx.x;
  for (int idx = t; idx < 4096; idx += 256) {
    int ic = idx >> 4;
    int ocl = idx & 15;
    Ws[idx] = w[(size_t)(n16 * 16 + ocl) * 20736 + ic * 81 + kp];
  }
  __syncthreads();
  for (int idx = t; idx < 4096; idx += 256) {
    int c = idx >> 9;          // k-chunk within this kp: 0..7
    int r = idx & 511;
    int ll = r >> 3, j = r & 7;
    int ic = c * 32 + ((ll >> 4) << 3) + j;
    g_wbF[(((size_t)kp * 8 + c) * 16 + n16) * 512 + r] = f2bf(Ws[ic * 16 + (ll & 15)]);
  }
}

// ---------------- conv1 + relu -> bf16 NHWC (register-blocked) ----------------
__global__ __launch_bounds__(256) void conv1_relu_k(
    const float* __restrict__ in, const float* __restrict__ w,
    const float* __restrict__ bias) {
  __shared__ float in_s[784];
  __shared__ float w_s[64 * 81];
  int b = blockIdx.x;
  int oc0 = blockIdx.y * 64;
  int t = threadIdx.x;
  for (int i = t; i < 784; i += 256) in_s[i] = in[b * 784 + i];
  for (int i = t; i < 64 * 81; i += 256) w_s[i] = w[oc0 * 81 + i];
  __syncthreads();

  int ocl = t & 63;
  int r = t >> 6;            // wave-uniform
  float w_r[81];
#pragma unroll
  for (int i = 0; i < 81; i++) w_r[i] = w_s[ocl * 81 + i];
  float bv = bias[oc0 + ocl];
  u16* outb = g_x1b + (size_t)b * 102400 + oc0 + ocl;

#pragma unroll
  for (int rr = 0; rr < 5; rr++) {
    int oy = r + rr * 4;     // wave-uniform
    float acc[20];
#pragma unroll
    for (int ox = 0; ox < 20; ox++) acc[ox] = bv;
#pragma unroll
    for (int ky = 0; ky < 9; ky++) {
      float in_r[28];
      const float* irow = &in_s[(oy + ky) * 28];
#pragma unroll
      for (int c = 0; c < 28; c++) in_r[c] = irow[c];   // broadcast reads
#pragma unroll
      for (int kx = 0; kx < 9; kx++) {
        float wv = w_r[ky * 9 + kx];
#pragma unroll
        for (int ox = 0; ox < 20; ox++)
          acc[ox] = fmaf(in_r[ox + kx], wv, acc[ox]);
      }
    }
#pragma unroll
    for (int ox = 0; ox < 20; ox++)
      outb[(oy * 20 + ox) * 256] = f2bf(fmaxf(acc[ox], 0.f));
  }
}

// ---------------- pc conv: bf16 MFMA GEMM, full-N blocks (R14 + int bofs) --
__global__ __launch_bounds__(256) void pc_mfma_k() {
  __shared__ u16 As[64 * 72];  // 64 rows x 64 k, padded row stride 72
  int t = threadIdx.x;
  int m0 = blockIdx.x * 64;
  int ks0 = blockIdx.y * KSLICE;
  u16* outp = g_y2p + (size_t)blockIdx.y * PS;

  int w = t >> 6, l = t & 63, quad = l >> 4, c15 = l & 15;
  int wm = w & 1, wn = w >> 1;

  int sr = t >> 3;
  int sc = t & 7;
  int fixed0, fixed1;
  {
    int m = m0 + sr;
    int bb = m / 36;
    int s = m - bb * 36;
    int oy = s / 6;
    int ox = s - oy * 6;
    fixed0 = bb * 102400 + oy * 10240 + ox * 512 + sc * 8;
    m += 32;
    bb = m / 36;
    s = m - bb * 36;
    oy = s / 6;
    ox = s - oy * 6;
    fixed1 = bb * 102400 + oy * 10240 + ox * 512 + sc * 8;
  }

  // B fragment offsets in elements (g_wbF spans 10.6MB -> 32-bit safe)
  int bofs[8];
#pragma unroll
  for (int g = 0; g < 2; g++)
#pragma unroll
    for (int jn = 0; jn < 4; jn++)
      bofs[g * 4 + jn] = ((g * 8 + wn * 4 + jn) << 9) + l * 8;

  f32x4 acc[2][8];
#pragma unroll
  for (int i = 0; i < 2; i++)
#pragma unroll
    for (int j = 0; j < 8; j++) acc[i][j] = (f32x4){0.f, 0.f, 0.f, 0.f};

  uint4 ap0, ap1;
  bf16x8 bpf[2][8];
  {
    int k0 = ks0;
    int kp = k0 >> 8, ic0 = k0 & 255;
    int ky = kp / 9, kx = kp - ky * 9;
    int off = ky * 5120 + kx * 256 + ic0;
    ap0 = *(const uint4*)(g_x1b + fixed0 + off);
    ap1 = *(const uint4*)(g_x1b + fixed1 + off);
    const u16* bp = g_wbF + ((k0 >> 5) << 13);
#pragma unroll
    for (int kk = 0; kk < 2; kk++)
#pragma unroll
      for (int jn = 0; jn < 8; jn++)
        bpf[kk][jn] = *(const bf16x8*)(bp + (kk << 13) + bofs[jn]);
  }

  for (int st = 0; st < NSTAGE; st++) {
    __syncthreads();
    *(uint4*)&As[sr * 72 + sc * 8] = ap0;
    *(uint4*)&As[(sr + 32) * 72 + sc * 8] = ap1;
    __syncthreads();
    if (st < NSTAGE - 1) {
      int k0 = ks0 + (st + 1) * 64;
      int kp = k0 >> 8, ic0 = k0 & 255;
      int ky = kp / 9, kx = kp - ky * 9;
      int off = ky * 5120 + kx * 256 + ic0;
      ap0 = *(const uint4*)(g_x1b + fixed0 + off);
      ap1 = *(const uint4*)(g_x1b + fixed1 + off);
    }
#pragma unroll
    for (int kk = 0; kk < 2; kk++) {
#pragma unroll
      for (int i = 0; i < 2; i++) {
        bf16x8 af = *(const bf16x8*)&As[(wm * 32 + i * 16 + c15) * 72 + kk * 32 + quad * 8];
#pragma unroll
        for (int jn = 0; jn < 8; jn++)
          acc[i][jn] = __builtin_amdgcn_mfma_f32_16x16x32_bf16(af, bpf[kk][jn], acc[i][jn], 0, 0, 0);
      }
    }
    if (st < NSTAGE - 1) {
      int k0n = ks0 + (st + 1) * 64;
      const u16* bp = g_wbF + ((k0n >> 5) << 13);
#pragma unroll
      for (int kk = 0; kk < 2; kk++)
#pragma unroll
        for (int jn = 0; jn < 8; jn++)
          bpf[kk][jn] = *(const bf16x8*)(bp + (kk << 13) + bofs[jn]);
    }
  }
#pragma unroll
  for (int i = 0; i < 2; i++)
#pragma unroll
    for (int g = 0; g < 2; g++)
#pragma unroll
      for (int jn = 0; jn < 4; jn++) {
        int col = g * 128 + wn * 64 + jn * 16 + c15;
#pragma unroll
        for (int rg = 0; rg < 4; rg++) {
          int row = m0 + wm * 32 + i * 16 + quad * 4 + rg;
          outp[(size_t)row * 256 + col] = f2bf(acc[i][g * 4 + jn][rg]);
        }
      }
}

// ---------------- squash primary capsules (coalesced row-wise) -------------
__global__ __launch_bounds__(256) void squash_u_k(const float* __restrict__ pcb) {
  __shared__ float xs[256];
  __shared__ float scs[32];
  int m = blockIdx.x;          // 0..9215
  int t = threadIdx.x;
  int b = m / 36;
  int s = m - b * 36;
  float x = pcb[t];
  const u16* base = g_y2p + (size_t)m * 256 + t;
#pragma unroll
  for (int q = 0; q < KSPLIT; q++) x += bf2f(base[(size_t)q * PS]);
  xs[t] = x;
  __syncthreads();
  if (t < 32) {
    float sq = 0.f;
#pragma unroll
    for (int p = 0; p < 8; p++) {
      float v = xs[t + p * 32];
      sq = fmaf(v, v, sq);
    }
    scs[t] = (sq / (1.f + sq)) * rsqrtf(sq + 1e-7f);
  }
  __syncthreads();
  int g = t & 31, p = t >> 5;
  g_u[((size_t)b * 1152 + g * 36 + s) * 8 + p] = x * scs[g];
}

// ---------------- WU einsum (bf16 output) ----------------
__global__ __launch_bounds__(256) void wu_k(const float* __restrict__ W) {
  __shared__ float W_s[8][161];
  __shared__ float u_s[32][8];
  int n = blockIdx.x;
  int b0 = blockIdx.y * 32;
  int t = threadIdx.x;
  const float* Wn = W + (size_t)n * 1280;
  for (int i = t; i < 1280; i += 256) {
    int cd = i >> 3, p = i & 7;
    W_s[p][cd] = Wn[i];
  }
  {
    int bl = t >> 3, p = t & 7;
    u_s[bl][p] = g_u[(size_t)(b0 + bl) * 9216 + n * 8 + p];
  }
  __syncthreads();
#pragma unroll
  for (int i = 0; i < 20; i++) {
    int idx = t + 256 * i;
    int bl = idx / 160;
    int cd = idx - bl * 160;
    float acc = 0.f;
#pragma unroll
    for (int p = 0; p < 8; p++) acc = fmaf(u_s[bl][p], W_s[p][cd], acc);
    g_WU[((size_t)(b0 + bl) * 1152 + n) * 160 + cd] = f2bf(acc);
  }
}

// ---------------- iter0 reduction (bf16 input) ----------------
__global__ __launch_bounds__(256) void red0_k() {
  int b = blockIdx.x;
  int chunk = blockIdx.y;
  int t = threadIdx.x;
  if (t >= 160) return;
  const u16* base = g_WU + ((size_t)b * 1152 + chunk * 144) * 160 + t;
  float acc = 0.f;
  for (int n = 0; n < 144; n++) acc += bf2f(base[(size_t)n * 160]);
  atomicAdd(&g_ssum[b * 160 + t], 0.1f * acc);
}

// ---------------- squash of class capsules ----------------
__global__ void squash_v_k(int slot, float* __restrict__ clf, int write_clf) {
  int b = blockIdx.x;
  int c = threadIdx.x;
  if (c >= 10) return;
  const float* s = g_ssum + slot * 40960 + b * 160 + c * 16;
  float sq = 0.f;
#pragma unroll
  for (int d = 0; d < 16; d++) sq = fmaf(s[d], s[d], sq);
  float scale = (sq / (1.f + sq)) * rsqrtf(sq + 1e-7f);
  float* vo = g_v + slot * 40960 + b * 160 + c * 16;
#pragma unroll
  for (int d = 0; d < 16; d++) vo[d] = s[d] * scale;
  if (write_clf) clf[b * 10 + c] = scale * sqrtf(sq);
}

// ---------------- routing iteration (bf16 WU input) ----------------
template <int IT>
__global__ __launch_bounds__(256) void routing_iter_k() {
  int b = blockIdx.x;
  int nb = blockIdx.y;
  int t = threadIdx.x;
  int lane = t & 15;
  int grp = t >> 4;

  const float* v0 = g_v;
  const float* v1 = g_v + 40960;
  float* ssum_out = g_ssum + IT * 40960;

  float v0r[10], v1r[10];
#pragma unroll
  for (int c = 0; c < 10; c++) v0r[c] = v0[b * 160 + c * 16 + lane];
  if (IT == 2) {
#pragma unroll
    for (int c = 0; c < 10; c++) v1r[c] = v1[b * 160 + c * 16 + lane];
  }

  float acc[10];
#pragma unroll
  for (int c = 0; c < 10; c++) acc[c] = 0.f;

  for (int ni = 0; ni < 9; ni++) {
    int n = nb * 144 + grp * 9 + ni;
    const u16* row = g_WU + ((size_t)b * 1152 + n) * 160;
    float wu[10];
#pragma unroll
    for (int c = 0; c < 10; c++) wu[c] = bf2f(row[c * 16 + lane]);

    float bij[10];
#pragma unroll
    for (int c = 0; c < 10; c++) {
      float x = v0r[c] * wu[c];
      x += __shfl_xor(x, 1);
      x += __shfl_xor(x, 2);
      x += __shfl_xor(x, 4);
      x += __shfl_xor(x, 8);
      bij[c] = 0.1f * x;
    }

    if (IT == 2) {
      float mx = bij[0];
#pragma unroll
      for (int c = 1; c < 10; c++) mx = fmaxf(mx, bij[c]);
      float e[10], ssum = 0.f;
#pragma unroll
      for (int c = 0; c < 10; c++) {
        e[c] = __expf(bij[c] - mx);
        ssum += e[c];
      }
      float inv = 1.f / ssum;
#pragma unroll
      for (int c = 0; c < 10; c++) {
        float x = v1r[c] * wu[c];
        x += __shfl_xor(x, 1);
        x += __shfl_xor(x, 2);
        x += __shfl_xor(x, 4);
        x += __shfl_xor(x, 8);
        bij[c] = bij[c] + (e[c] * inv) * x;
      }
    }

    float mx = bij[0];
#pragma unroll
    for (int c = 1; c < 10; c++) mx = fmaxf(mx, bij[c]);
    float e[10], ssum = 0.f;
#pragma unroll
    for (int c = 0; c < 10; c++) {
      e[c] = __expf(bij[c] - mx);
      ssum += e[c];
    }
    float inv = 1.f / ssum;
#pragma unroll
    for (int c = 0; c < 10; c++) acc[c] = fmaf(e[c] * inv, wu[c], acc[c]);
  }
#pragma unroll
  for (int c = 0; c < 10; c++)
    atomicAdd(&ssum_out[b * 160 + c * 16 + lane], acc[c]);
}

// ---------------- decoder ----------------
__global__ __launch_bounds__(256) void dec1_k(const int* __restrict__ labels,
                                              const float* __restrict__ w1,
                                              const float* __restrict__ b1) {
  int b = blockIdx.y;
  int j = blockIdx.x * 256 + threadIdx.x;
  int lab = labels[b];
  const float* vv = g_v + 2 * 40960 + b * 160 + lab * 16;
  float acc = b1[j];
#pragma unroll
  for (int d = 0; d < 16; d++)
    acc = fmaf(vv[d], w1[(size_t)(lab * 16 + d) * 512 + j], acc);
  g_h1[b * 512 + j] = fmaxf(acc, 0.f);
}

// dec2: 2 batches per block — w2 stream reused 2x. Grid (4, 128).
__global__ __launch_bounds__(256) void dec2_k(const float* __restrict__ w2,
                                              const float* __restrict__ b2) {
  __shared__ float h_s[2][512];
  int b0 = blockIdx.y * 2;
  int j = blockIdx.x * 256 + threadIdx.x;
  int t = threadIdx.x;
  for (int i = t; i < 1024; i += 256) h_s[i >> 9][i & 511] = g_h1[b0 * 512 + i];
  __syncthreads();
  float a0 = b2[j], a1 = a0;
#pragma unroll 8
  for (int k = 0; k < 512; k++) {
    float wv = w2[(size_t)k * 1024 + j];
    a0 = fmaf(h_s[0][k], wv, a0);
    a1 = fmaf(h_s[1][k], wv, a1);
  }
  g_h2[b0 * 1024 + j] = fmaxf(a0, 0.f);
  g_h2[(b0 + 1) * 1024 + j] = fmaxf(a1, 0.f);
}

// dec3: 2 batches per block — w3 stream reused 2x. Grid (4, 128).
__global__ __launch_bounds__(256) void dec3_k(const float* __restrict__ w3,
                                              const float* __restrict__ b3,
                                              float* __restrict__ out) {
  __shared__ float h_s[2][1024];
  int b0 = blockIdx.y * 2;
  int t = threadIdx.x;
  for (int i = t; i < 2048; i += 256) h_s[i >> 10][i & 1023] = g_h2[b0 * 1024 + i];
  __syncthreads();
  if (t >= 196) return;
  int j = blockIdx.x * 196 + t;
  float a0 = b3[j], a1 = a0;
#pragma unroll 8
  for (int k = 0; k < 1024; k++) {
    float wv = w3[(size_t)k * 784 + j];
    a0 = fmaf(h_s[0][k], wv, a0);
    a1 = fmaf(h_s[1][k], wv, a1);
  }
  out[2560 + b0 * 784 + j] = 1.f / (1.f + __expf(-a0));
  out[2560 + (b0 + 1) * 784 + j] = 1.f / (1.f + __expf(-a1));
}

// ---------------------------------------------------------------------------
extern "C" void kernel_launch(void* const* d_in, const int* in_sizes, int n_in,
                              void* d_out, int out_size, void* d_ws,
                              size_t ws_size, hipStream_t stream) {
  const float* inputs = (const float*)d_in[0];
  const int* labels = (const int*)d_in[1];
  const float* conv1_w = (const float*)d_in[2];
  const float* conv1_b = (const float*)d_in[3];
  const float* pc_w = (const float*)d_in[4];
  const float* pc_b = (const float*)d_in[5];
  const float* rw = (const float*)d_in[6];
  const float* dw1 = (const float*)d_in[7];
  const float* db1 = (const float*)d_in[8];
  const float* dw2 = (const float*)d_in[9];
  const float* db2 = (const float*)d_in[10];
  const float* dw3 = (const float*)d_in[11];
  const float* db3 = (const float*)d_in[12];
  float* out = (float*)d_out;
  (void)d_ws; (void)ws_size; (void)in_sizes; (void)n_in;

  zero_ssum_k<<<(3 * 256 * 160 + 255) / 256, 256, 0, stream>>>();
  wconv_k<<<dim3(16, 81), 256, 0, stream>>>(pc_w);
  conv1_relu_k<<<dim3(256, 4), 256, 0, stream>>>(inputs, conv1_w, conv1_b);
  pc_mfma_k<<<dim3(144, KSPLIT), 256, 0, stream>>>();
  squash_u_k<<<9216, 256, 0, stream>>>(pc_b);
  wu_k<<<dim3(1152, 8), 256, 0, stream>>>(rw);
  red0_k<<<dim3(256, 8), 256, 0, stream>>>();
  squash_v_k<<<256, 64, 0, stream>>>(0, nullptr, 0);
  routing_iter_k<1><<<dim3(256, 8), 256, 0, stream>>>();
  squash_v_k<<<256, 64, 0, stream>>>(1, nullptr, 0);
  routing_iter_k<2><<<dim3(256, 8), 256, 0, stream>>>();
  squash_v_k<<<256, 64, 0, stream>>>(2, out, 1);
  dec1_k<<<dim3(2, 256), 256, 0, stream>>>(labels, dw1, db1);
  dec2_k<<<dim3(4, 128), 256, 0, stream>>>(dw2, db2);
  dec3_k<<<dim3(4, 128), 256, 0, stream>>>(dw3, db3, out);
}

// Round 19
// 718.526 us; speedup vs baseline: 3.0590x; 1.0332x over previous
//
#include <hip/hip_runtime.h>
#include <math.h>

// ---------------------------------------------------------------------------
// CapsuleNet forward. R19: pc-conv A staging via __builtin_amdgcn_global_load_lds
// (async direct-to-LDS, width 16) with xor-swizzled chunk layout (unpadded LDS,
// source-side permutation -> ~2-way bank aliasing = free). Removes the A VGPR
// round-trip (~20 VALU + ~12 VGPR/stage). Everything else identical to R18
// (742us best). If this regresses, revert to R18 = structural plateau.
// ---------------------------------------------------------------------------

typedef unsigned short u16;
typedef short bf16x8 __attribute__((ext_vector_type(8)));
typedef float f32x4 __attribute__((ext_vector_type(4)));

#define PS 2359296   // 9216*256, one y2 partial buffer
#define KSPLIT 9
#define KSLICE 2304  // 20736/9
#define NSTAGE 36    // 2304/64

__device__ u16 g_x1b[256 * 400 * 256];          // conv1 out NHWC bf16 (52 MB)
__device__ u16 g_wbF[648 * 16 * 512];           // pc_w bf16, MFMA frag order (10.6 MB)
__device__ u16 g_y2p[(size_t)KSPLIT * PS];      // pc GEMM K-partials bf16 (42.5 MB)
__device__ float g_u[256 * 1152 * 8];           // squashed primary caps
__device__ u16 g_WU[(size_t)256 * 1152 * 160];  // u_hat bf16 (94.4 MB)
__device__ float g_ssum[3 * 256 * 160];
__device__ float g_v[3 * 256 * 160];
__device__ float g_h1[256 * 512];
__device__ float g_h2[256 * 1024];

__device__ __forceinline__ u16 f2bf(float f) {
  union { float f; unsigned u; } v; v.f = f;
  unsigned r = (v.u + 0x7FFFu + ((v.u >> 16) & 1u)) >> 16;  // RNE
  return (u16)r;
}
__device__ __forceinline__ float bf2f(u16 h) {
  union { unsigned u; float f; } v; v.u = ((unsigned)h) << 16;
  return v.f;
}

// ---------------- zero the atomic accumulators ----------------
__global__ __launch_bounds__(256) void zero_ssum_k() {
  int i = blockIdx.x * 256 + threadIdx.x;
  if (i < 3 * 256 * 160) g_ssum[i] = 0.f;
}

// ------ pc_w fp32 [oc][ic][kp] -> bf16 fragment order --------------------
__global__ __launch_bounds__(256) void wconv_k(const float* __restrict__ w) {
  __shared__ float Ws[256 * 16];   // [ic][ocl] 16 KB
  int n16 = blockIdx.x;   // 0..15
  int kp = blockIdx.y;    // 0..80
  int t = threadIdx.x;
  for (int idx = t; idx < 4096; idx += 256) {
    int ic = idx >> 4;
    int ocl = idx & 15;
    Ws[idx] = w[(size_t)(n16 * 16 + ocl) * 20736 + ic * 81 + kp];
  }
  __syncthreads();
  for (int idx = t; idx < 4096; idx += 256) {
    int c = idx >> 9;          // k-chunk within this kp: 0..7
    int r = idx & 511;
    int ll = r >> 3, j = r & 7;
    int ic = c * 32 + ((ll >> 4) << 3) + j;
    g_wbF[(((size_t)kp * 8 + c) * 16 + n16) * 512 + r] = f2bf(Ws[ic * 16 + (ll & 15)]);
  }
}

// ---------------- conv1 + relu -> bf16 NHWC (register-blocked) ----------------
__global__ __launch_bounds__(256) void conv1_relu_k(
    const float* __restrict__ in, const float* __restrict__ w,
    const float* __restrict__ bias) {
  __shared__ float in_s[784];
  __shared__ float w_s[64 * 81];
  int b = blockIdx.x;
  int oc0 = blockIdx.y * 64;
  int t = threadIdx.x;
  for (int i = t; i < 784; i += 256) in_s[i] = in[b * 784 + i];
  for (int i = t; i < 64 * 81; i += 256) w_s[i] = w[oc0 * 81 + i];
  __syncthreads();

  int ocl = t & 63;
  int r = t >> 6;            // wave-uniform
  float w_r[81];
#pragma unroll
  for (int i = 0; i < 81; i++) w_r[i] = w_s[ocl * 81 + i];
  float bv = bias[oc0 + ocl];
  u16* outb = g_x1b + (size_t)b * 102400 + oc0 + ocl;

#pragma unroll
  for (int rr = 0; rr < 5; rr++) {
    int oy = r + rr * 4;     // wave-uniform
    float acc[20];
#pragma unroll
    for (int ox = 0; ox < 20; ox++) acc[ox] = bv;
#pragma unroll
    for (int ky = 0; ky < 9; ky++) {
      float in_r[28];
      const float* irow = &in_s[(oy + ky) * 28];
#pragma unroll
      for (int c = 0; c < 28; c++) in_r[c] = irow[c];   // broadcast reads
#pragma unroll
      for (int kx = 0; kx < 9; kx++) {
        float wv = w_r[ky * 9 + kx];
#pragma unroll
        for (int ox = 0; ox < 20; ox++)
          acc[ox] = fmaf(in_r[ox + kx], wv, acc[ox]);
      }
    }
#pragma unroll
    for (int ox = 0; ox < 20; ox++)
      outb[(oy * 20 + ox) * 256] = f2bf(fmaxf(acc[ox], 0.f));
  }
}

// ---------------- pc conv: bf16 MFMA GEMM, GLD-staged A (xor swizzle) ------
__global__ __launch_bounds__(256) void pc_mfma_k() {
  __shared__ u16 As[64 * 64];  // unpadded; chunk index xor-swizzled by row&7
  int t = threadIdx.x;
  int m0 = blockIdx.x * 64;
  int ks0 = blockIdx.y * KSLICE;
  u16* outp = g_y2p + (size_t)blockIdx.y * PS;

  int w = t >> 6, l = t & 63, quad = l >> 4, c15 = l & 15;
  int wm = w & 1, wn = w >> 1;

  // A staging: thread t fills physical chunk (t&7) of rows sr and sr+32;
  // content = logical chunk (t&7)^(sr&7) (source-side xor swizzle).
  int sr = t >> 3;
  int sc = t & 7;
  int cch = sc ^ (sr & 7);
  int fixed0, fixed1;
  {
    int m = m0 + sr;
    int bb = m / 36;
    int s = m - bb * 36;
    int oy = s / 6;
    int ox = s - oy * 6;
    fixed0 = bb * 102400 + oy * 10240 + ox * 512 + cch * 8;
    m += 32;
    bb = m / 36;
    s = m - bb * 36;
    oy = s / 6;
    ox = s - oy * 6;
    fixed1 = bb * 102400 + oy * 10240 + ox * 512 + cch * 8;
  }
  // wave-uniform LDS bases: wave w covers bytes w*1024 (+4096 for upper rows)
  u16* lds0 = &As[(t >> 6) * 512];
  u16* lds1 = &As[2048 + (t >> 6) * 512];

  // B fragment offsets in elements (g_wbF spans 10.6MB -> 32-bit safe)
  int bofs[8];
#pragma unroll
  for (int g = 0; g < 2; g++)
#pragma unroll
    for (int jn = 0; jn < 4; jn++)
      bofs[g * 4 + jn] = ((g * 8 + wn * 4 + jn) << 9) + l * 8;

  f32x4 acc[2][8];
#pragma unroll
  for (int i = 0; i < 2; i++)
#pragma unroll
    for (int j = 0; j < 8; j++) acc[i][j] = (f32x4){0.f, 0.f, 0.f, 0.f};

  bf16x8 bpf[2][8];
  {
    const u16* bp = g_wbF + ((ks0 >> 5) << 13);
#pragma unroll
    for (int kk = 0; kk < 2; kk++)
#pragma unroll
      for (int jn = 0; jn < 8; jn++)
        bpf[kk][jn] = *(const bf16x8*)(bp + (kk << 13) + bofs[jn]);
  }

  for (int st = 0; st < NSTAGE; st++) {
    int k0 = ks0 + st * 64;
    int kp = k0 >> 8, ic0 = k0 & 255;
    int ky = kp / 9, kx = kp - ky * 9;
    int off = ky * 5120 + kx * 256 + ic0;
    __syncthreads();   // all waves done reading previous stage
    __builtin_amdgcn_global_load_lds(
        (const __attribute__((address_space(1))) unsigned*)(g_x1b + fixed0 + off),
        (__attribute__((address_space(3))) unsigned*)lds0, 16, 0, 0);
    __builtin_amdgcn_global_load_lds(
        (const __attribute__((address_space(1))) unsigned*)(g_x1b + fixed1 + off),
        (__attribute__((address_space(3))) unsigned*)lds1, 16, 0, 0);
    __syncthreads();   // vmcnt drain -> As ready
    // compute with B prefetched last iteration (bpf), A from swizzled LDS
#pragma unroll
    for (int kk = 0; kk < 2; kk++) {
#pragma unroll
      for (int i = 0; i < 2; i++) {
        int rr = wm * 32 + i * 16 + c15;
        int pch = (kk * 4 + quad) ^ (rr & 7);
        bf16x8 af = *(const bf16x8*)&As[rr * 64 + pch * 8];
#pragma unroll
        for (int jn = 0; jn < 8; jn++)
          acc[i][jn] = __builtin_amdgcn_mfma_f32_16x16x32_bf16(af, bpf[kk][jn], acc[i][jn], 0, 0, 0);
      }
    }
    // B prefetch one stage ahead (L2-resident, short latency)
    if (st < NSTAGE - 1) {
      int k0n = ks0 + (st + 1) * 64;
      const u16* bp = g_wbF + ((k0n >> 5) << 13);
#pragma unroll
      for (int kk = 0; kk < 2; kk++)
#pragma unroll
        for (int jn = 0; jn < 8; jn++)
          bpf[kk][jn] = *(const bf16x8*)(bp + (kk << 13) + bofs[jn]);
    }
  }
  // epilogue: C/D map col=lane&15, row=quad*4+reg
#pragma unroll
  for (int i = 0; i < 2; i++)
#pragma unroll
    for (int g = 0; g < 2; g++)
#pragma unroll
      for (int jn = 0; jn < 4; jn++) {
        int col = g * 128 + wn * 64 + jn * 16 + c15;
#pragma unroll
        for (int rg = 0; rg < 4; rg++) {
          int row = m0 + wm * 32 + i * 16 + quad * 4 + rg;
          outp[(size_t)row * 256 + col] = f2bf(acc[i][g * 4 + jn][rg]);
        }
      }
}

// ---------------- squash primary capsules (coalesced row-wise) -------------
__global__ __launch_bounds__(256) void squash_u_k(const float* __restrict__ pcb) {
  __shared__ float xs[256];
  __shared__ float scs[32];
  int m = blockIdx.x;          // 0..9215
  int t = threadIdx.x;
  int b = m / 36;
  int s = m - b * 36;
  float x = pcb[t];
  const u16* base = g_y2p + (size_t)m * 256 + t;
#pragma unroll
  for (int q = 0; q < KSPLIT; q++) x += bf2f(base[(size_t)q * PS]);
  xs[t] = x;
  __syncthreads();
  if (t < 32) {
    float sq = 0.f;
#pragma unroll
    for (int p = 0; p < 8; p++) {
      float v = xs[t + p * 32];
      sq = fmaf(v, v, sq);
    }
    scs[t] = (sq / (1.f + sq)) * rsqrtf(sq + 1e-7f);
  }
  __syncthreads();
  int g = t & 31, p = t >> 5;
  g_u[((size_t)b * 1152 + g * 36 + s) * 8 + p] = x * scs[g];
}

// ---------------- WU einsum (bf16 output) ----------------
__global__ __launch_bounds__(256) void wu_k(const float* __restrict__ W) {
  __shared__ float W_s[8][161];
  __shared__ float u_s[32][8];
  int n = blockIdx.x;
  int b0 = blockIdx.y * 32;
  int t = threadIdx.x;
  const float* Wn = W + (size_t)n * 1280;
  for (int i = t; i < 1280; i += 256) {
    int cd = i >> 3, p = i & 7;
    W_s[p][cd] = Wn[i];
  }
  {
    int bl = t >> 3, p = t & 7;
    u_s[bl][p] = g_u[(size_t)(b0 + bl) * 9216 + n * 8 + p];
  }
  __syncthreads();
#pragma unroll
  for (int i = 0; i < 20; i++) {
    int idx = t + 256 * i;
    int bl = idx / 160;
    int cd = idx - bl * 160;
    float acc = 0.f;
#pragma unroll
    for (int p = 0; p < 8; p++) acc = fmaf(u_s[bl][p], W_s[p][cd], acc);
    g_WU[((size_t)(b0 + bl) * 1152 + n) * 160 + cd] = f2bf(acc);
  }
}

// ---------------- iter0 reduction (bf16 input) ----------------
__global__ __launch_bounds__(256) void red0_k() {
  int b = blockIdx.x;
  int chunk = blockIdx.y;
  int t = threadIdx.x;
  if (t >= 160) return;
  const u16* base = g_WU + ((size_t)b * 1152 + chunk * 144) * 160 + t;
  float acc = 0.f;
  for (int n = 0; n < 144; n++) acc += bf2f(base[(size_t)n * 160]);
  atomicAdd(&g_ssum[b * 160 + t], 0.1f * acc);
}

// ---------------- squash of class capsules ----------------
__global__ void squash_v_k(int slot, float* __restrict__ clf, int write_clf) {
  int b = blockIdx.x;
  int c = threadIdx.x;
  if (c >= 10) return;
  const float* s = g_ssum + slot * 40960 + b * 160 + c * 16;
  float sq = 0.f;
#pragma unroll
  for (int d = 0; d < 16; d++) sq = fmaf(s[d], s[d], sq);
  float scale = (sq / (1.f + sq)) * rsqrtf(sq + 1e-7f);
  float* vo = g_v + slot * 40960 + b * 160 + c * 16;
#pragma unroll
  for (int d = 0; d < 16; d++) vo[d] = s[d] * scale;
  if (write_clf) clf[b * 10 + c] = scale * sqrtf(sq);
}

// ---------------- routing iteration (bf16 WU input) ----------------
template <int IT>
__global__ __launch_bounds__(256) void routing_iter_k() {
  int b = blockIdx.x;
  int nb = blockIdx.y;
  int t = threadIdx.x;
  int lane = t & 15;
  int grp = t >> 4;

  const float* v0 = g_v;
  const float* v1 = g_v + 40960;
  float* ssum_out = g_ssum + IT * 40960;

  float v0r[10], v1r[10];
#pragma unroll
  for (int c = 0; c < 10; c++) v0r[c] = v0[b * 160 + c * 16 + lane];
  if (IT == 2) {
#pragma unroll
    for (int c = 0; c < 10; c++) v1r[c] = v1[b * 160 + c * 16 + lane];
  }

  float acc[10];
#pragma unroll
  for (int c = 0; c < 10; c++) acc[c] = 0.f;

  for (int ni = 0; ni < 9; ni++) {
    int n = nb * 144 + grp * 9 + ni;
    const u16* row = g_WU + ((size_t)b * 1152 + n) * 160;
    float wu[10];
#pragma unroll
    for (int c = 0; c < 10; c++) wu[c] = bf2f(row[c * 16 + lane]);

    float bij[10];
#pragma unroll
    for (int c = 0; c < 10; c++) {
      float x = v0r[c] * wu[c];
      x += __shfl_xor(x, 1);
      x += __shfl_xor(x, 2);
      x += __shfl_xor(x, 4);
      x += __shfl_xor(x, 8);
      bij[c] = 0.1f * x;
    }

    if (IT == 2) {
      float mx = bij[0];
#pragma unroll
      for (int c = 1; c < 10; c++) mx = fmaxf(mx, bij[c]);
      float e[10], ssum = 0.f;
#pragma unroll
      for (int c = 0; c < 10; c++) {
        e[c] = __expf(bij[c] - mx);
        ssum += e[c];
      }
      float inv = 1.f / ssum;
#pragma unroll
      for (int c = 0; c < 10; c++) {
        float x = v1r[c] * wu[c];
        x += __shfl_xor(x, 1);
        x += __shfl_xor(x, 2);
        x += __shfl_xor(x, 4);
        x += __shfl_xor(x, 8);
        bij[c] = bij[c] + (e[c] * inv) * x;
      }
    }

    float mx = bij[0];
#pragma unroll
    for (int c = 1; c < 10; c++) mx = fmaxf(mx, bij[c]);
    float e[10], ssum = 0.f;
#pragma unroll
    for (int c = 0; c < 10; c++) {
      e[c] = __expf(bij[c] - mx);
      ssum += e[c];
    }
    float inv = 1.f / ssum;
#pragma unroll
    for (int c = 0; c < 10; c++) acc[c] = fmaf(e[c] * inv, wu[c], acc[c]);
  }
#pragma unroll
  for (int c = 0; c < 10; c++)
    atomicAdd(&ssum_out[b * 160 + c * 16 + lane], acc[c]);
}

// ---------------- decoder ----------------
__global__ __launch_bounds__(256) void dec1_k(const int* __restrict__ labels,
                                              const float* __restrict__ w1,
                                              const float* __restrict__ b1) {
  int b = blockIdx.y;
  int j = blockIdx.x * 256 + threadIdx.x;
  int lab = labels[b];
  const float* vv = g_v + 2 * 40960 + b * 160 + lab * 16;
  float acc = b1[j];
#pragma unroll
  for (int d = 0; d < 16; d++)
    acc = fmaf(vv[d], w1[(size_t)(lab * 16 + d) * 512 + j], acc);
  g_h1[b * 512 + j] = fmaxf(acc, 0.f);
}

// dec2: 2 batches per block — w2 stream reused 2x. Grid (4, 128).
__global__ __launch_bounds__(256) void dec2_k(const float* __restrict__ w2,
                                              const float* __restrict__ b2) {
  __shared__ float h_s[2][512];
  int b0 = blockIdx.y * 2;
  int j = blockIdx.x * 256 + threadIdx.x;
  int t = threadIdx.x;
  for (int i = t; i < 1024; i += 256) h_s[i >> 9][i & 511] = g_h1[b0 * 512 + i];
  __syncthreads();
  float a0 = b2[j], a1 = a0;
#pragma unroll 8
  for (int k = 0; k < 512; k++) {
    float wv = w2[(size_t)k * 1024 + j];
    a0 = fmaf(h_s[0][k], wv, a0);
    a1 = fmaf(h_s[1][k], wv, a1);
  }
  g_h2[b0 * 1024 + j] = fmaxf(a0, 0.f);
  g_h2[(b0 + 1) * 1024 + j] = fmaxf(a1, 0.f);
}

// dec3: 2 batches per block — w3 stream reused 2x. Grid (4, 128).
__global__ __launch_bounds__(256) void dec3_k(const float* __restrict__ w3,
                                              const float* __restrict__ b3,
                                              float* __restrict__ out) {
  __shared__ float h_s[2][1024];
  int b0 = blockIdx.y * 2;
  int t = threadIdx.x;
  for (int i = t; i < 2048; i += 256) h_s[i >> 10][i & 1023] = g_h2[b0 * 1024 + i];
  __syncthreads();
  if (t >= 196) return;
  int j = blockIdx.x * 196 + t;
  float a0 = b3[j], a1 = a0;
#pragma unroll 8
  for (int k = 0; k < 1024; k++) {
    float wv = w3[(size_t)k * 784 + j];
    a0 = fmaf(h_s[0][k], wv, a0);
    a1 = fmaf(h_s[1][k], wv, a1);
  }
  out[2560 + b0 * 784 + j] = 1.f / (1.f + __expf(-a0));
  out[2560 + (b0 + 1) * 784 + j] = 1.f / (1.f + __expf(-a1));
}

// ---------------------------------------------------------------------------
extern "C" void kernel_launch(void* const* d_in, const int* in_sizes, int n_in,
                              void* d_out, int out_size, void* d_ws,
                              size_t ws_size, hipStream_t stream) {
  const float* inputs = (const float*)d_in[0];
  const int* labels = (const int*)d_in[1];
  const float* conv1_w = (const float*)d_in[2];
  const float* conv1_b = (const float*)d_in[3];
  const float* pc_w = (const float*)d_in[4];
  const float* pc_b = (const float*)d_in[5];
  const float* rw = (const float*)d_in[6];
  const float* dw1 = (const float*)d_in[7];
  const float* db1 = (const float*)d_in[8];
  const float* dw2 = (const float*)d_in[9];
  const float* db2 = (const float*)d_in[10];
  const float* dw3 = (const float*)d_in[11];
  const float* db3 = (const float*)d_in[12];
  float* out = (float*)d_out;
  (void)d_ws; (void)ws_size; (void)in_sizes; (void)n_in;

  zero_ssum_k<<<(3 * 256 * 160 + 255) / 256, 256, 0, stream>>>();
  wconv_k<<<dim3(16, 81), 256, 0, stream>>>(pc_w);
  conv1_relu_k<<<dim3(256, 4), 256, 0, stream>>>(inputs, conv1_w, conv1_b);
  pc_mfma_k<<<dim3(144, KSPLIT), 256, 0, stream>>>();
  squash_u_k<<<9216, 256, 0, stream>>>(pc_b);
  wu_k<<<dim3(1152, 8), 256, 0, stream>>>(rw);
  red0_k<<<dim3(256, 8), 256, 0, stream>>>();
  squash_v_k<<<256, 64, 0, stream>>>(0, nullptr, 0);
  routing_iter_k<1><<<dim3(256, 8), 256, 0, stream>>>();
  squash_v_k<<<256, 64, 0, stream>>>(1, nullptr, 0);
  routing_iter_k<2><<<dim3(256, 8), 256, 0, stream>>>();
  squash_v_k<<<256, 64, 0, stream>>>(2, out, 1);
  dec1_k<<<dim3(2, 256), 256, 0, stream>>>(labels, dw1, db1);
  dec2_k<<<dim3(4, 128), 256, 0, stream>>>(dw2, db2);
  dec3_k<<<dim3(4, 128), 256, 0, stream>>>(dw3, db3, out);
}